// Round 1
// 522.284 us; speedup vs baseline: 1.1535x; 1.1535x over previous
//
#include <hip/hip_runtime.h>

// LoraLinear NF4: out = x @ W_eff^T, W_eff = NF4[codes]*absmax + 2*(lora_B @ lora_A)
// M=8192 (4*2048), N=4096, K=4096. f16 MFMA GEMM.
// R3: gemm ported from m97 structure (128^2, 2-phase, ~810 TF ceiling) to the
// 256^2 8-phase template (T1 XCD swizzle + T2 LDS XOR swizzle + T3/T4 counted
// vmcnt + T5 setprio). BM=BN=256, BK=64, 8 waves (2Mx4N), per-wave 128x64.
// LDS 128 KiB = 2 dbuf x {A,B} x 2 half-regions (128 rows x 64 f16 each).
// Schedule per K-tile t (4 phases; quadrant order (mh,nh)=(0,0),(0,1),(1,1),(1,0)):
//   ph1: read A(mh0)+B(nh0) | stage (t+1).A1 | bar | lgkm0 | 16 MFMA | bar
//   ph2: read B(nh1)        | stage (t+1).B0 | bar | lgkm0 | 16 MFMA | bar
//   ph3: read A(mh1)        | stage (t+1).B1 | bar | lgkm0 | 16 MFMA | bar
//   ph4: read B(nh0)        | stage (t+2).A0 | s_waitcnt vmcnt(2) | bar | ...
// vmcnt(2) leaves only the newest half-stage in flight; everything tile t+1
// needs is retired. Stages into a region always issue >=1 closing-barrier after
// that region's last ds_read was lgkm-waited -> no overwrite race.
// T2 swizzle: physical chunk = logical chunk ^ (row&7) (16B chunks, 128B rows);
// applied as inverse-permuted GLOBAL source (LDS dest linear, rule #21) and
// XOR'd ds_read addresses; per-16-lane phase => 2 lanes/bank (free).

typedef _Float16 half8 __attribute__((ext_vector_type(8)));
typedef float f32x4 __attribute__((ext_vector_type(4)));

#define M_DIM 8192
#define N_DIM 4096
#define K_DIM 4096
#define NT (K_DIM / 64)

__constant__ float NF4C[16] = {
    -1.0f, -0.6961928009986877f, -0.5250730514526367f, -0.39491748809814453f,
    -0.28444138169288635f, -0.18477343022823334f, -0.09105003625154495f, 0.0f,
    0.07958029955625534f, 0.16093020141124725f, 0.24611230194568634f, 0.33791524171829224f,
    0.44070982933044434f, 0.5626170039176941f, 0.7229568362236023f, 1.0f};

__device__ __forceinline__ void gl16(void* lds, const void* g) {
  // async global->LDS, 16B/lane; LDS dest = wave-uniform base + lane*16
  __builtin_amdgcn_global_load_lds(
      (const __attribute__((address_space(1))) void*)g,
      (__attribute__((address_space(3))) void*)lds, 16, 0, 0);
}

// ---------------- prep_x: fp32 -> f16 cast of x ----------------
__global__ __launch_bounds__(256) void prep_x(const float4* __restrict__ x,
                                              half8* __restrict__ xh) {
  size_t i = (size_t)blockIdx.x * 256 + threadIdx.x;  // one half8 (8 elems) per thread
  float4 a = x[2 * i];
  float4 b = x[2 * i + 1];
  half8 h;
  h[0] = (_Float16)a.x; h[1] = (_Float16)a.y; h[2] = (_Float16)a.z; h[3] = (_Float16)a.w;
  h[4] = (_Float16)b.x; h[5] = (_Float16)b.y; h[6] = (_Float16)b.z; h[7] = (_Float16)b.w;
  xh[i] = h;
}

// ---------------- prep_w: dequant NF4 + fold 2*B@A, write f16 ----------------
#define PWP 132  // padded leading dim
__global__ __launch_bounds__(256) void prep_w(const float* __restrict__ lora_A,
                                              const float* __restrict__ lora_B,
                                              const float* __restrict__ absmax,
                                              const int* __restrict__ codes,
                                              _Float16* __restrict__ Wc) {
  __shared__ float At[64 * PWP];  // At[r][ii] = lora_A[r][i0+ii]
  __shared__ float Bt[64 * PWP];  // Bt[r][oo] = lora_B[o0+oo][r]
  __shared__ float nf4s[16];
  const int tid = threadIdx.x;
  const int bxi = blockIdx.x & 31;   // i-tile (4096/128)
  const int byo = blockIdx.x >> 5;   // o-tile
  const int i0 = bxi * 128;
  const int o0 = byo * 128;
  if (tid < 16) nf4s[tid] = NF4C[tid];
  for (int idx = tid; idx < 8192; idx += 256) {
    int r = idx >> 7, ii = idx & 127;
    At[r * PWP + ii] = lora_A[(size_t)r * 4096 + i0 + ii];
  }
  for (int idx = tid; idx < 8192; idx += 256) {
    int oo = idx >> 6, r = idx & 63;
    Bt[r * PWP + oo] = lora_B[(size_t)(o0 + oo) * 64 + r];
  }
  __syncthreads();
  const int tx = tid & 15;   // col group: cols tx*8..+8
  const int ty = tid >> 4;   // row group: rows ty*8..+8
  float accw[8][8];
#pragma unroll
  for (int i = 0; i < 8; ++i)
#pragma unroll
    for (int j = 0; j < 8; ++j) accw[i][j] = 0.0f;
  for (int r = 0; r < 64; ++r) {
    float4 a0 = *(const float4*)&At[r * PWP + tx * 8];
    float4 a1 = *(const float4*)&At[r * PWP + tx * 8 + 4];
    float4 b0 = *(const float4*)&Bt[r * PWP + ty * 8];
    float4 b1 = *(const float4*)&Bt[r * PWP + ty * 8 + 4];
    float av[8] = {a0.x, a0.y, a0.z, a0.w, a1.x, a1.y, a1.z, a1.w};
    float bv[8] = {b0.x, b0.y, b0.z, b0.w, b1.x, b1.y, b1.z, b1.w};
#pragma unroll
    for (int i = 0; i < 8; ++i)
#pragma unroll
      for (int j = 0; j < 8; ++j) accw[i][j] += bv[i] * av[j];
  }
#pragma unroll
  for (int i = 0; i < 8; ++i) {
    const int o_g = o0 + ty * 8 + i;
    const int* crow = codes + (size_t)o_g * 4096 + i0 + tx * 8;
    int4 c0 = *(const int4*)crow;
    int4 c1 = *(const int4*)(crow + 4);
    const float am = absmax[o_g * 64 + (i0 >> 6) + (tx >> 3)];
    half8 h;
    h[0] = (_Float16)(nf4s[c0.x] * am + 2.0f * accw[i][0]);
    h[1] = (_Float16)(nf4s[c0.y] * am + 2.0f * accw[i][1]);
    h[2] = (_Float16)(nf4s[c0.z] * am + 2.0f * accw[i][2]);
    h[3] = (_Float16)(nf4s[c0.w] * am + 2.0f * accw[i][3]);
    h[4] = (_Float16)(nf4s[c1.x] * am + 2.0f * accw[i][4]);
    h[5] = (_Float16)(nf4s[c1.y] * am + 2.0f * accw[i][5]);
    h[6] = (_Float16)(nf4s[c1.z] * am + 2.0f * accw[i][6]);
    h[7] = (_Float16)(nf4s[c1.w] * am + 2.0f * accw[i][7]);
    *(half8*)(Wc + (size_t)o_g * 4096 + i0 + tx * 8) = h;
  }
}

// ---------------- gemm: C[M,N] = Xh[M,K] * Wc[N,K]^T (f16 MFMA, 256^2 8-phase) --
// LDS f16 offsets: region(buf,isB,half) = buf*32768 + isB*16384 + half*8192.
// Within region: row r (0..127), 16B chunk c (0..7); physical c = logical ^ (r&7).

#define BAR __builtin_amdgcn_s_barrier()
#define LGKM0 asm volatile("s_waitcnt lgkmcnt(0)" ::: "memory")

__global__ __launch_bounds__(512, 2) void gemm(const _Float16* __restrict__ Xh,
                                               const _Float16* __restrict__ Wc,
                                               float* __restrict__ out) {
  __shared__ _Float16 lds[65536];  // 128 KiB
  const int tid = threadIdx.x;
  const int lane = tid & 63;
  const int w = tid >> 6;  // wave 0..7; 2M x 4N: wm=(w>>2)*128, wn=(w&3)*64

  // T1: bijective XCD swizzle (512 wgs, 8 XCDs, 64 per XCD)
  const int swz = (blockIdx.x & 7) * 64 + (blockIdx.x >> 3);
  const int by = swz >> 4;  // 0..31 (M/256)
  const int bx = swz & 15;  // 0..15 (N/256)

  // fragment-read addressing (T2 swizzle on read side)
  const int m16 = lane & 15;
  const int quad = lane >> 4;
  const int csw = (quad ^ (m16 & 7)) * 8;       // swizzled chunk(kk=0) * 8 f16
  const int aoff0 = m16 * 64 + csw;             // kk=0
  const int aoff1 = m16 * 64 + (csw ^ 32);      // kk=1 (chunk ^= 4)
  const int ha = w >> 2;                        // wave's A half-region
  const int hboff = ((w & 3) >> 1) * 8192 + (w & 1) * 4096;  // B region + row sub

  // staging source (T2 inverse swizzle on global source; LDS dest linear)
  const int r0 = tid >> 3;                      // row 0..63 (load1: +64)
  const int lc = (tid & 7) ^ (r0 & 7);          // logical chunk for this dest slot
  const _Float16* gAbase = Xh + (size_t)(by * 256 + r0) * K_DIM + lc * 8;
  const _Float16* gBbase = Wc + (size_t)(bx * 256 + r0) * K_DIM + lc * 8;

#define STAGE_A(H, BUF, T)                                                   \
  do {                                                                       \
    _Float16* d_ = lds + (BUF) * 32768 + (H) * 8192 + w * 512;               \
    const _Float16* s_ = gAbase + (size_t)((H) * 128) * K_DIM + (T) * 64;    \
    gl16(d_, s_);                                                            \
    gl16(d_ + 4096, s_ + (size_t)64 * K_DIM);                                \
  } while (0)
#define STAGE_B(H, BUF, T)                                                   \
  do {                                                                       \
    _Float16* d_ = lds + (BUF) * 32768 + 16384 + (H) * 8192 + w * 512;       \
    const _Float16* s_ = gBbase + (size_t)((H) * 128) * K_DIM + (T) * 64;    \
    gl16(d_, s_);                                                            \
    gl16(d_ + 4096, s_ + (size_t)64 * K_DIM);                                \
  } while (0)

  f32x4 acc[8][4];
#pragma unroll
  for (int m = 0; m < 8; ++m)
#pragma unroll
    for (int n = 0; n < 4; ++n) acc[m][n] = (f32x4){0.f, 0.f, 0.f, 0.f};

  half8 af[4][2];  // A frags of current mh (4 fm x 2 kk)
  half8 bf[2][2];  // B frags of current nh (2 fn x 2 kk)

#define LOAD_A(MH)                                                           \
  do {                                                                       \
    _Pragma("unroll") for (int fm = 0; fm < 4; ++fm) {                       \
      af[fm][0] = *(const half8*)(rA + (MH) * 4096 + fm * 1024 + aoff0);     \
      af[fm][1] = *(const half8*)(rA + (MH) * 4096 + fm * 1024 + aoff1);     \
    }                                                                        \
  } while (0)
#define LOAD_B(NH)                                                           \
  do {                                                                       \
    _Pragma("unroll") for (int fn = 0; fn < 2; ++fn) {                       \
      bf[fn][0] = *(const half8*)(rBw + (NH) * 2048 + fn * 1024 + aoff0);    \
      bf[fn][1] = *(const half8*)(rBw + (NH) * 2048 + fn * 1024 + aoff1);    \
    }                                                                        \
  } while (0)
#define MFMA16(MH, NH)                                                       \
  do {                                                                       \
    __builtin_amdgcn_s_setprio(1);                                           \
    _Pragma("unroll") for (int fm = 0; fm < 4; ++fm)                         \
        _Pragma("unroll") for (int fn = 0; fn < 2; ++fn) {                   \
      acc[(MH) * 4 + fm][(NH) * 2 + fn] = __builtin_amdgcn_mfma_f32_16x16x32_f16( \
          af[fm][0], bf[fn][0], acc[(MH) * 4 + fm][(NH) * 2 + fn], 0, 0, 0); \
      acc[(MH) * 4 + fm][(NH) * 2 + fn] = __builtin_amdgcn_mfma_f32_16x16x32_f16( \
          af[fm][1], bf[fn][1], acc[(MH) * 4 + fm][(NH) * 2 + fn], 0, 0, 0); \
    }                                                                        \
    __builtin_amdgcn_s_setprio(0);                                           \
  } while (0)

  // prologue: tile0 fully + tile1.A0; counted wait keeps newest stage in flight
  STAGE_A(0, 0, 0);
  STAGE_A(1, 0, 0);
  STAGE_B(0, 0, 0);
  STAGE_B(1, 0, 0);
  STAGE_A(0, 1, 1);
  asm volatile("s_waitcnt vmcnt(2)" ::: "memory");
  BAR;

  for (int t = 0; t < NT; ++t) {
    const int bsel = t & 1;
    const int bn = bsel ^ 1;
    const _Float16* rA = lds + bsel * 32768 + ha * 8192;
    const _Float16* rBw = lds + bsel * 32768 + 16384 + hboff;
    const bool more1 = (t + 1 < NT);
    // ---- phase 1: (mh0, nh0)
    LOAD_A(0);
    LOAD_B(0);
    if (more1) STAGE_A(1, bn, t + 1);
    BAR; LGKM0;
    MFMA16(0, 0);
    BAR;
    // ---- phase 2: (mh0, nh1)
    LOAD_B(1);
    if (more1) STAGE_B(0, bn, t + 1);
    BAR; LGKM0;
    MFMA16(0, 1);
    BAR;
    // ---- phase 3: (mh1, nh1)
    LOAD_A(1);
    if (more1) STAGE_B(1, bn, t + 1);
    BAR; LGKM0;
    MFMA16(1, 1);
    BAR;
    // ---- phase 4: (mh1, nh0)  — the once-per-tile counted vmcnt
    LOAD_B(0);
    if (t + 2 < NT) {
      STAGE_A(0, bsel, t + 2);
      asm volatile("s_waitcnt vmcnt(2)" ::: "memory");
    } else {
      asm volatile("s_waitcnt vmcnt(0)" ::: "memory");
    }
    BAR; LGKM0;
    MFMA16(1, 0);
    BAR;
  }

  // epilogue: C/D layout col=lane&15, row=quad*4+reg
  const size_t rowbase = (size_t)by * 256 + ha * 128 + quad * 4;
  const int colbase = bx * 256 + (w & 3) * 64 + m16;
#pragma unroll
  for (int m = 0; m < 8; ++m) {
#pragma unroll
    for (int r = 0; r < 4; ++r) {
      float* po = out + (rowbase + m * 16 + r) * N_DIM + colbase;
      po[0]  = acc[m][0][r];
      po[16] = acc[m][1][r];
      po[32] = acc[m][2][r];
      po[48] = acc[m][3][r];
    }
  }
}

extern "C" void kernel_launch(void* const* d_in, const int* in_sizes, int n_in,
                              void* d_out, int out_size, void* d_ws, size_t ws_size,
                              hipStream_t stream) {
  const float* x      = (const float*)d_in[0];
  const float* lora_A = (const float*)d_in[1];
  const float* lora_B = (const float*)d_in[2];
  const float* absmax = (const float*)d_in[3];
  const int*   codes  = (const int*)d_in[4];
  float* out = (float*)d_out;

  _Float16* Xh = (_Float16*)d_ws;                    // 8192*4096 f16 = 64 MiB
  _Float16* Wc = Xh + (size_t)M_DIM * K_DIM;         // 4096*4096 f16 = 32 MiB

  hipLaunchKernelGGL(prep_x, dim3((M_DIM * K_DIM) / (8 * 256)), dim3(256), 0, stream,
                     (const float4*)x, (half8*)Xh);
  hipLaunchKernelGGL(prep_w, dim3((N_DIM / 128) * (K_DIM / 128)), dim3(256), 0, stream,
                     lora_A, lora_B, absmax, codes, Wc);
  hipLaunchKernelGGL(gemm, dim3((M_DIM / 256) * (N_DIM / 256)), dim3(512), 0, stream,
                     Xh, Wc, out);
}